// Round 2
// baseline (973.915 us; speedup 1.0000x reference)
//
#include <hip/hip_runtime.h>

// WindowAttention3D: B=1024, N1=256, N2=128, C=128, NH=4, hd=32, nW=64
// out = [x (1024*256*128 f32)] ++ [attn (1024*4*256*128 f32)]

typedef __attribute__((ext_vector_type(8))) short s16x8;
typedef __attribute__((ext_vector_type(4))) short s16x4;
typedef __attribute__((ext_vector_type(4))) float f32x4;

static __device__ __forceinline__ unsigned short f2bf(float f) {
  union { float f; unsigned u; } v; v.f = f;
  unsigned r = v.u + 0x7FFFu + ((v.u >> 16) & 1u);
  return (unsigned short)(r >> 16);
}

// ---------------- prep: weights->bf16, combined bias+mask table ----------------
// bm[w][h][q][n2] = rpb[rel_index[q][n2]][h] + mask[w][q][n2]   (f32, 32 MB)
__global__ void kw_prep(const float* __restrict__ qw, const float* __restrict__ kvw,
                        const float* __restrict__ pw, const float* __restrict__ rpb,
                        const int* __restrict__ relidx, const float* __restrict__ mask,
                        unsigned short* __restrict__ qwb, unsigned short* __restrict__ kvwb,
                        unsigned short* __restrict__ pwb, float* __restrict__ bm) {
  int tid = blockIdx.x * 256 + threadIdx.x;
  int stride = gridDim.x * 256;
  for (int i = tid; i < 65536; i += stride) {
    if (i < 16384)      qwb[i] = f2bf(qw[i]);
    else if (i < 49152) kvwb[i - 16384] = f2bf(kvw[i - 16384]);
    else                pwb[i - 49152] = f2bf(pw[i - 49152]);
  }
  for (int i = tid; i < 2097152; i += stride) {
    int wdw = i >> 15, j = i & 32767;
    int rel = relidx[j];
    float4 tv = *(const float4*)(rpb + rel * 4);
    float mk = mask[i];
    float* d = bm + (size_t)(wdw * 4) * 32768 + j;
    d[0]      = tv.x + mk;
    d[32768]  = tv.y + mk;
    d[65536]  = tv.z + mk;
    d[98304]  = tv.w + mk;
  }
}

// ---------------- q projection: qh = (q @ qw^T + qb) * scale, bf16 ----------------
__global__ __launch_bounds__(256) void kq(const float* __restrict__ q,
    const unsigned short* __restrict__ qwb, const float* __restrict__ qb,
    unsigned short* __restrict__ qh) {
  __shared__ unsigned short qL[64][136];
  int b = blockIdx.x >> 2, q0 = (blockIdx.x & 3) << 6;
  int t = threadIdx.x;
  const float4* src = (const float4*)(q + (b * 256 + q0) * 128);
#pragma unroll
  for (int i = 0; i < 8; ++i) {
    int idx = t + i * 256;                 // 2048 float4 = 64 rows x 128 f32
    float4 v = src[idx];
    unsigned short* d = &qL[idx >> 5][(idx & 31) * 4];
    d[0] = f2bf(v.x); d[1] = f2bf(v.y); d[2] = f2bf(v.z); d[3] = f2bf(v.w);
  }
  __syncthreads();
  int w = t >> 6, l = t & 63, lm = l & 15, lg = l >> 4;
  f32x4 acc[8];
#pragma unroll
  for (int i = 0; i < 8; ++i) acc[i] = (f32x4){0.f, 0.f, 0.f, 0.f};
#pragma unroll
  for (int kk = 0; kk < 4; ++kk) {
    s16x8 a = *(const s16x8*)&qL[w * 16 + lm][kk * 32 + lg * 8];
#pragma unroll
    for (int ct = 0; ct < 8; ++ct) {
      s16x8 bf = *(const s16x8*)(qwb + (ct * 16 + lm) * 128 + kk * 32 + lg * 8);
      acc[ct] = __builtin_amdgcn_mfma_f32_16x16x32_bf16(a, bf, acc[ct], 0, 0, 0);
    }
  }
  const float SC = 0.17677669529663687f;   // 32^-0.5
#pragma unroll
  for (int ct = 0; ct < 8; ++ct) {
    int col = ct * 16 + lm;
    float bb = qb[col];
#pragma unroll
    for (int r = 0; r < 4; ++r) {
      int row = q0 + w * 16 + lg * 4 + r;
      qh[(b * 256 + row) * 128 + col] = f2bf((acc[ct][r] + bb) * SC);
    }
  }
}

// ---------------- kv projection: k row-major bf16, v transposed bf16 ----------------
__global__ __launch_bounds__(256) void kkv(const float* __restrict__ kv,
    const unsigned short* __restrict__ kvwb, const float* __restrict__ kvb,
    unsigned short* __restrict__ kws, unsigned short* __restrict__ vT) {
  __shared__ unsigned short kvL[64][136];
  int b = blockIdx.x >> 1, r0 = (blockIdx.x & 1) << 6;
  int t = threadIdx.x;
  const float4* src = (const float4*)(kv + (b * 128 + r0) * 128);
#pragma unroll
  for (int i = 0; i < 8; ++i) {
    int idx = t + i * 256;
    float4 v = src[idx];
    unsigned short* d = &kvL[idx >> 5][(idx & 31) * 4];
    d[0] = f2bf(v.x); d[1] = f2bf(v.y); d[2] = f2bf(v.z); d[3] = f2bf(v.w);
  }
  __syncthreads();
  int w = t >> 6, l = t & 63, lm = l & 15, lg = l >> 4;
  f32x4 acc[16];
#pragma unroll
  for (int i = 0; i < 16; ++i) acc[i] = (f32x4){0.f, 0.f, 0.f, 0.f};
#pragma unroll
  for (int kk = 0; kk < 4; ++kk) {
    s16x8 a = *(const s16x8*)&kvL[w * 16 + lm][kk * 32 + lg * 8];
#pragma unroll
    for (int ct = 0; ct < 16; ++ct) {
      s16x8 bf = *(const s16x8*)(kvwb + (ct * 16 + lm) * 128 + kk * 32 + lg * 8);
      acc[ct] = __builtin_amdgcn_mfma_f32_16x16x32_bf16(a, bf, acc[ct], 0, 0, 0);
    }
  }
#pragma unroll
  for (int ct = 0; ct < 16; ++ct) {
    int col = ct * 16 + lm;
    float bb = kvb[col];
    if (col < 128) {            // k part: [b][n2][col]
#pragma unroll
      for (int r = 0; r < 4; ++r) {
        int n2 = r0 + w * 16 + lg * 4 + r;
        kws[(b * 128 + n2) * 128 + col] = f2bf(acc[ct][r] + bb);
      }
    } else {                    // v part: transposed vT[b][d][n2]
      int d = col - 128;
      int n2b = r0 + w * 16 + lg * 4;
      s16x4 pack;
#pragma unroll
      for (int r = 0; r < 4; ++r) pack[r] = f2bf(acc[ct][r] + bb);
      *(s16x4*)(vT + (b * 128 + d) * 128 + n2b) = pack;
    }
  }
}

// ---------------- fused attention + out-proj, one block per b ----------------
__global__ __launch_bounds__(512) void katt2(const unsigned short* __restrict__ qh,
    const unsigned short* __restrict__ kws, const unsigned short* __restrict__ vT,
    const float* __restrict__ bm, const unsigned short* __restrict__ pwb,
    const float* __restrict__ pb, float* __restrict__ attn_out,
    float* __restrict__ xout) {
  __shared__ unsigned short kL[128][136];   // k[b][n2][d], all heads
  __shared__ unsigned short vTL[128][136];  // vT[b][d][n2], all heads
  __shared__ unsigned short pL[8][32][136]; // per-wave P / X tile
  int b = blockIdx.x;
  int t = threadIdx.x;
  const unsigned short* ksrc = kws + (size_t)b * 16384;
  const unsigned short* vsrc = vT + (size_t)b * 16384;
#pragma unroll
  for (int i = 0; i < 4; ++i) {
    int idx = t + i * 512;                  // 2048 segs: 128 rows x 16 segs of 8
    int row = idx >> 4, seg = idx & 15;
    *(s16x8*)&kL[row][seg * 8]  = *(const s16x8*)(ksrc + row * 128 + seg * 8);
    *(s16x8*)&vTL[row][seg * 8] = *(const s16x8*)(vsrc + row * 128 + seg * 8);
  }
  __syncthreads();
  int w = t >> 6, l = t & 63, lm = l & 15, lg = l >> 4;
  int q0 = w * 32;
  const float* bmb = bm + (size_t)((b & 63) * 4) * 32768;
  float* attnb = attn_out + (size_t)b * 4 * 32768;
  const f32x4 zero = {0.f, 0.f, 0.f, 0.f};
  f32x4 Oall[4][2][2];
#pragma unroll
  for (int h = 0; h < 4; ++h)
#pragma unroll
    for (int rt = 0; rt < 2; ++rt)
#pragma unroll
      for (int cd = 0; cd < 2; ++cd) Oall[h][rt][cd] = zero;

#pragma unroll
  for (int h = 0; h < 4; ++h) {
    // ---- S = qh_h @ k_h^T (K=32: one MFMA per 16x16 tile) ----
    s16x8 aq[2];
#pragma unroll
    for (int rt = 0; rt < 2; ++rt)
      aq[rt] = *(const s16x8*)(qh + ((size_t)b * 256 + q0 + rt * 16 + lm) * 128 + h * 32 + lg * 8);
    f32x4 S[2][8];
#pragma unroll
    for (int ct = 0; ct < 8; ++ct) {
      s16x8 bk = *(const s16x8*)&kL[ct * 16 + lm][h * 32 + lg * 8];
#pragma unroll
      for (int rt = 0; rt < 2; ++rt)
        S[rt][ct] = __builtin_amdgcn_mfma_f32_16x16x32_bf16(aq[rt], bk, zero, 0, 0, 0);
    }
    // ---- +bm, softmax (rows live in 16-lane groups) ----
    const float* bmh = bmb + h * 32768;
    float* attnh = attnb + h * 32768;
#pragma unroll
    for (int rt = 0; rt < 2; ++rt) {
#pragma unroll
      for (int r = 0; r < 4; ++r) {
        int qr = q0 + rt * 16 + lg * 4 + r;
        float v[8];
        float m = -1e30f;
#pragma unroll
        for (int ct = 0; ct < 8; ++ct) {
          float x = S[rt][ct][r] + bmh[qr * 128 + ct * 16 + lm];
          v[ct] = x;
          m = fmaxf(m, x);
        }
#pragma unroll
        for (int d = 1; d < 16; d <<= 1) m = fmaxf(m, __shfl_xor(m, d));
        float s = 0.f;
#pragma unroll
        for (int ct = 0; ct < 8; ++ct) { v[ct] = __expf(v[ct] - m); s += v[ct]; }
#pragma unroll
        for (int d = 1; d < 16; d <<= 1) s += __shfl_xor(s, d);
        float inv = 1.0f / s;
        int prow = rt * 16 + lg * 4 + r;
#pragma unroll
        for (int ct = 0; ct < 8; ++ct) {
          float pv = v[ct] * inv;
          int col = ct * 16 + lm;
          attnh[qr * 128 + col] = pv;       // exact fp32 attn output
          pL[w][prow][col] = f2bf(pv);
        }
      }
    }
    // ---- O_h += P @ v (vT rows h*32..h*32+32) ----
#pragma unroll
    for (int kk = 0; kk < 4; ++kk) {
      s16x8 ap[2];
#pragma unroll
      for (int rt = 0; rt < 2; ++rt)
        ap[rt] = *(const s16x8*)&pL[w][rt * 16 + lm][kk * 32 + lg * 8];
#pragma unroll
      for (int cd = 0; cd < 2; ++cd) {
        s16x8 bv = *(const s16x8*)&vTL[h * 32 + cd * 16 + lm][kk * 32 + lg * 8];
#pragma unroll
        for (int rt = 0; rt < 2; ++rt)
          Oall[h][rt][cd] = __builtin_amdgcn_mfma_f32_16x16x32_bf16(ap[rt], bv, Oall[h][rt][cd], 0, 0, 0);
      }
    }
  }
  // ---- write O (all heads) into per-wave LDS as bf16 X tile ----
#pragma unroll
  for (int h = 0; h < 4; ++h)
#pragma unroll
    for (int rt = 0; rt < 2; ++rt)
#pragma unroll
      for (int cd = 0; cd < 2; ++cd)
#pragma unroll
        for (int r = 0; r < 4; ++r)
          pL[w][rt * 16 + lg * 4 + r][h * 32 + cd * 16 + lm] = f2bf(Oall[h][rt][cd][r]);
  // ---- out-proj: x = X @ pw^T + pb ----
  f32x4 acc[2][8];
#pragma unroll
  for (int rt = 0; rt < 2; ++rt)
#pragma unroll
    for (int ct = 0; ct < 8; ++ct) acc[rt][ct] = zero;
#pragma unroll
  for (int kk = 0; kk < 4; ++kk) {
    s16x8 a[2];
#pragma unroll
    for (int rt = 0; rt < 2; ++rt)
      a[rt] = *(const s16x8*)&pL[w][rt * 16 + lm][kk * 32 + lg * 8];
#pragma unroll
    for (int ct = 0; ct < 8; ++ct) {
      s16x8 bf = *(const s16x8*)(pwb + (ct * 16 + lm) * 128 + kk * 32 + lg * 8);
#pragma unroll
      for (int rt = 0; rt < 2; ++rt)
        acc[rt][ct] = __builtin_amdgcn_mfma_f32_16x16x32_bf16(a[rt], bf, acc[rt][ct], 0, 0, 0);
    }
  }
#pragma unroll
  for (int ct = 0; ct < 8; ++ct) {
    int col = ct * 16 + lm;
    float bb = pb[col];
#pragma unroll
    for (int rt = 0; rt < 2; ++rt)
#pragma unroll
      for (int r = 0; r < 4; ++r) {
        int row = q0 + rt * 16 + lg * 4 + r;
        xout[((size_t)b * 256 + row) * 128 + col] = acc[rt][ct][r] + bb;
      }
  }
}

extern "C" void kernel_launch(void* const* d_in, const int* in_sizes, int n_in,
                              void* d_out, int out_size, void* d_ws, size_t ws_size,
                              hipStream_t stream) {
  const float* q    = (const float*)d_in[0];
  const float* kv   = (const float*)d_in[1];
  const float* mask = (const float*)d_in[2];
  const float* qw   = (const float*)d_in[3];
  const float* qb   = (const float*)d_in[4];
  const float* kvw  = (const float*)d_in[5];
  const float* kvb  = (const float*)d_in[6];
  const float* pw   = (const float*)d_in[7];
  const float* pb   = (const float*)d_in[8];
  const float* rpb  = (const float*)d_in[9];
  const int* relidx = (const int*)d_in[10];

  float* xout = (float*)d_out;
  float* attn = xout + (size_t)1024 * 256 * 128;   // 33,554,432

  char* ws = (char*)d_ws;
  unsigned short* qwb  = (unsigned short*)ws;                 // 32 KB
  unsigned short* kvwb = (unsigned short*)(ws + 32768);       // 64 KB
  unsigned short* pwb  = (unsigned short*)(ws + 98304);       // 32 KB
  float*          bm   = (float*)(ws + 131072);               // 32 MB
  unsigned short* qh   = (unsigned short*)(ws + 131072 + 33554432);  // 64 MB
  unsigned short* kws  = qh  + (size_t)33554432;              // 32 MB
  unsigned short* vT   = kws + (size_t)16777216;              // 32 MB

  kw_prep<<<2048, 256, 0, stream>>>(qw, kvw, pw, rpb, relidx, mask, qwb, kvwb, pwb, bm);
  kq<<<4096, 256, 0, stream>>>(q, qwb, qb, qh);
  kkv<<<2048, 256, 0, stream>>>(kv, kvwb, kvb, kws, vT);
  katt2<<<1024, 512, 0, stream>>>(qh, kws, vT, bm, pwb, pb, attn, xout);
}

// Round 4
// 570.326 us; speedup vs baseline: 1.7076x; 1.7076x over previous
//
#include <hip/hip_runtime.h>

// WindowAttention3D: B=1024, N1=256, N2=128, C=128, NH=4, hd=32, nW=64
// out = [x (1024*256*128 f32)] ++ [attn (1024*4*256*128 f32)]

typedef __attribute__((ext_vector_type(8))) short s16x8;
typedef __attribute__((ext_vector_type(4))) short s16x4;
typedef __attribute__((ext_vector_type(4))) float f32x4;

static __device__ __forceinline__ unsigned short f2bf(float f) {
  union { float f; unsigned u; } v; v.f = f;
  unsigned r = v.u + 0x7FFFu + ((v.u >> 16) & 1u);
  return (unsigned short)(r >> 16);
}

// ---------------- prep: weights->bf16, combined bias+mask table ----------------
// bm[w][h][q][n2] = rpb[rel_index[q][n2]][h] + mask[w][q][n2]   (f32, 32 MB)
__global__ void kw_prep(const float* __restrict__ qw, const float* __restrict__ kvw,
                        const float* __restrict__ pw, const float* __restrict__ rpb,
                        const int* __restrict__ relidx, const float* __restrict__ mask,
                        unsigned short* __restrict__ qwb, unsigned short* __restrict__ kvwb,
                        unsigned short* __restrict__ pwb, float* __restrict__ bm) {
  int tid = blockIdx.x * 256 + threadIdx.x;
  int stride = gridDim.x * 256;
  for (int i = tid; i < 65536; i += stride) {
    if (i < 16384)      qwb[i] = f2bf(qw[i]);
    else if (i < 49152) kvwb[i - 16384] = f2bf(kvw[i - 16384]);
    else                pwb[i - 49152] = f2bf(pw[i - 49152]);
  }
  for (int i = tid; i < 2097152; i += stride) {
    int wdw = i >> 15, j = i & 32767;
    int rel = relidx[j];
    float4 tv = *(const float4*)(rpb + rel * 4);
    float mk = mask[i];
    float* d = bm + (size_t)(wdw * 4) * 32768 + j;
    d[0]      = tv.x + mk;
    d[32768]  = tv.y + mk;
    d[65536]  = tv.z + mk;
    d[98304]  = tv.w + mk;
  }
}

// ---------------- q projection: qh[b][h][q][32] = (q @ qw^T + qb) * scale ----------------
__global__ __launch_bounds__(256) void kq(const float* __restrict__ q,
    const unsigned short* __restrict__ qwb, const float* __restrict__ qb,
    unsigned short* __restrict__ qh) {
  __shared__ unsigned short qL[64][136];
  int b = blockIdx.x >> 2, q0 = (blockIdx.x & 3) << 6;
  int t = threadIdx.x;
  const float4* src = (const float4*)(q + (b * 256 + q0) * 128);
#pragma unroll
  for (int i = 0; i < 8; ++i) {
    int idx = t + i * 256;                 // 2048 float4 = 64 rows x 128 f32
    float4 v = src[idx];
    unsigned short* d = &qL[idx >> 5][(idx & 31) * 4];
    d[0] = f2bf(v.x); d[1] = f2bf(v.y); d[2] = f2bf(v.z); d[3] = f2bf(v.w);
  }
  __syncthreads();
  int w = t >> 6, l = t & 63, lm = l & 15, lg = l >> 4;
  f32x4 acc[8];
#pragma unroll
  for (int i = 0; i < 8; ++i) acc[i] = (f32x4){0.f, 0.f, 0.f, 0.f};
#pragma unroll
  for (int kk = 0; kk < 4; ++kk) {
    s16x8 a = *(const s16x8*)&qL[w * 16 + lm][kk * 32 + lg * 8];
#pragma unroll
    for (int ct = 0; ct < 8; ++ct) {
      s16x8 bf = *(const s16x8*)(qwb + (ct * 16 + lm) * 128 + kk * 32 + lg * 8);
      acc[ct] = __builtin_amdgcn_mfma_f32_16x16x32_bf16(a, bf, acc[ct], 0, 0, 0);
    }
  }
  const float SC = 0.17677669529663687f;   // 32^-0.5
#pragma unroll
  for (int ct = 0; ct < 8; ++ct) {
    int col = ct * 16 + lm;
    int h = col >> 5, dh = col & 31;
    float bb = qb[col];
#pragma unroll
    for (int r = 0; r < 4; ++r) {
      int row = q0 + w * 16 + lg * 4 + r;
      qh[((size_t)(b * 4 + h) * 256 + row) * 32 + dh] = f2bf((acc[ct][r] + bb) * SC);
    }
  }
}

// ---------------- kv projection: k[b][h][n2][32], vT[b][h][dh][n2] ----------------
__global__ __launch_bounds__(256) void kkv(const float* __restrict__ kv,
    const unsigned short* __restrict__ kvwb, const float* __restrict__ kvb,
    unsigned short* __restrict__ kws, unsigned short* __restrict__ vT) {
  __shared__ unsigned short kvL[64][136];
  int b = blockIdx.x >> 1, r0 = (blockIdx.x & 1) << 6;
  int t = threadIdx.x;
  const float4* src = (const float4*)(kv + (b * 128 + r0) * 128);
#pragma unroll
  for (int i = 0; i < 8; ++i) {
    int idx = t + i * 256;
    float4 v = src[idx];
    unsigned short* d = &kvL[idx >> 5][(idx & 31) * 4];
    d[0] = f2bf(v.x); d[1] = f2bf(v.y); d[2] = f2bf(v.z); d[3] = f2bf(v.w);
  }
  __syncthreads();
  int w = t >> 6, l = t & 63, lm = l & 15, lg = l >> 4;
  f32x4 acc[16];
#pragma unroll
  for (int i = 0; i < 16; ++i) acc[i] = (f32x4){0.f, 0.f, 0.f, 0.f};
#pragma unroll
  for (int kk = 0; kk < 4; ++kk) {
    s16x8 a = *(const s16x8*)&kvL[w * 16 + lm][kk * 32 + lg * 8];
#pragma unroll
    for (int ct = 0; ct < 16; ++ct) {
      s16x8 bf = *(const s16x8*)(kvwb + (ct * 16 + lm) * 128 + kk * 32 + lg * 8);
      acc[ct] = __builtin_amdgcn_mfma_f32_16x16x32_bf16(a, bf, acc[ct], 0, 0, 0);
    }
  }
#pragma unroll
  for (int ct = 0; ct < 16; ++ct) {
    int col = ct * 16 + lm;
    float bb = kvb[col];
    if (col < 128) {            // k part: [b][h][n2][dh]
      int h = col >> 5, dh = col & 31;
#pragma unroll
      for (int r = 0; r < 4; ++r) {
        int n2 = r0 + w * 16 + lg * 4 + r;
        kws[((size_t)(b * 4 + h) * 128 + n2) * 32 + dh] = f2bf(acc[ct][r] + bb);
      }
    } else {                    // v part: transposed vT[b][h][dh][n2]
      int d = col - 128;
      int n2b = r0 + w * 16 + lg * 4;
      s16x4 pack;
#pragma unroll
      for (int r = 0; r < 4; ++r) pack[r] = (short)f2bf(acc[ct][r] + bb);
      *(s16x4*)(vT + ((size_t)b * 128 + d) * 128 + n2b) = pack;
    }
  }
}

// ---------------- fused attention per (b, h), transposed fragments ----------------
__global__ __launch_bounds__(256) void katt3(const unsigned short* __restrict__ qh,
    const unsigned short* __restrict__ kws, const unsigned short* __restrict__ vT,
    const float* __restrict__ bm, float* __restrict__ attn_out,
    unsigned short* __restrict__ xp) {
  __shared__ unsigned short kL[128][40];    // k_h [n2][dh]
  __shared__ unsigned short vTL[32][136];   // vT_h [dh][n2]
  __shared__ unsigned short pL[4][32][136]; // per-wave P [q][n2] bf16
  int b = blockIdx.x >> 2, h = blockIdx.x & 3;
  int t = threadIdx.x;
  const unsigned short* ksrc = kws + (size_t)(b * 4 + h) * 4096;
  const unsigned short* vsrc = vT + (size_t)(b * 4 + h) * 4096;
#pragma unroll
  for (int i = 0; i < 2; ++i) {
    int idx = t + i * 256;                   // 512 segs: 128 rows x 4 segs of 8
    *(s16x8*)&kL[idx >> 2][(idx & 3) * 8] = *(const s16x8*)(ksrc + idx * 8);
  }
#pragma unroll
  for (int i = 0; i < 2; ++i) {
    int idx = t + i * 256;                   // 512 segs: 32 rows x 16 segs of 8
    *(s16x8*)&vTL[idx >> 4][(idx & 15) * 8] = *(const s16x8*)(vsrc + idx * 8);
  }
  __syncthreads();
  int w = t >> 6, l = t & 63, lm = l & 15, lg = l >> 4;
  const unsigned short* qsrc = qh + (size_t)(b * 4 + h) * 8192;
  const float* bmh = bm + (size_t)((b & 63) * 4 + h) * 32768;
  float* attnh = attn_out + (size_t)(b * 4 + h) * 32768;
  const f32x4 zero = {0.f, 0.f, 0.f, 0.f};

  for (int p = 0; p < 2; ++p) {
    int qbase = p * 128 + w * 32;
#pragma unroll
    for (int qt = 0; qt < 2; ++qt) {
      int q = qbase + qt * 16 + lm;
      // B-operand = q rows (N dim), direct from global (coalesced 1KB/instr)
      s16x8 bq = *(const s16x8*)(qsrc + q * 32 + lg * 8);
      f32x4 S[8];  // S^T[n2][q]: row n2 = ct*16+lg*4+r, col q = lm
#pragma unroll
      for (int ct = 0; ct < 8; ++ct) {
        s16x8 ak = *(const s16x8*)&kL[ct * 16 + lm][lg * 8];
        S[ct] = __builtin_amdgcn_mfma_f32_16x16x32_bf16(ak, bq, zero, 0, 0, 0);
      }
      // + bm (float4), softmax: 30 in-lane ops + 2 shuffles
      float m = -1e30f;
#pragma unroll
      for (int ct = 0; ct < 8; ++ct) {
        float4 bv = *(const float4*)(bmh + q * 128 + ct * 16 + lg * 4);
        S[ct][0] += bv.x; S[ct][1] += bv.y; S[ct][2] += bv.z; S[ct][3] += bv.w;
        m = fmaxf(m, fmaxf(fmaxf(S[ct][0], S[ct][1]), fmaxf(S[ct][2], S[ct][3])));
      }
      m = fmaxf(m, __shfl_xor(m, 16));
      m = fmaxf(m, __shfl_xor(m, 32));
      float s = 0.f;
#pragma unroll
      for (int ct = 0; ct < 8; ++ct) {
#pragma unroll
        for (int r = 0; r < 4; ++r) { S[ct][r] = __expf(S[ct][r] - m); s += S[ct][r]; }
      }
      s += __shfl_xor(s, 16);
      s += __shfl_xor(s, 32);
      float inv = 1.0f / s;
      float* arow = attnh + q * 128;
#pragma unroll
      for (int ct = 0; ct < 8; ++ct) {
        f32x4 pv = { S[ct][0] * inv, S[ct][1] * inv, S[ct][2] * inv, S[ct][3] * inv };
        __builtin_nontemporal_store(pv, (f32x4*)(arow + ct * 16 + lg * 4));
        s16x4 pk;
        pk[0] = (short)f2bf(pv.x); pk[1] = (short)f2bf(pv.y);
        pk[2] = (short)f2bf(pv.z); pk[3] = (short)f2bf(pv.w);
        *(s16x4*)&pL[w][qt * 16 + lm][ct * 16 + lg * 4] = pk;
      }
    }
    // ---- O^T = vT @ P^T: row d (A = vTL), col q (B = pL) ----
    f32x4 O[2][2];   // [cd][qt]
#pragma unroll
    for (int cd = 0; cd < 2; ++cd)
#pragma unroll
      for (int qt = 0; qt < 2; ++qt) O[cd][qt] = zero;
#pragma unroll
    for (int kk = 0; kk < 4; ++kk) {
      s16x8 av[2], bp[2];
#pragma unroll
      for (int cd = 0; cd < 2; ++cd) av[cd] = *(const s16x8*)&vTL[cd * 16 + lm][kk * 32 + lg * 8];
#pragma unroll
      for (int qt = 0; qt < 2; ++qt) bp[qt] = *(const s16x8*)&pL[w][qt * 16 + lm][kk * 32 + lg * 8];
#pragma unroll
      for (int cd = 0; cd < 2; ++cd)
#pragma unroll
        for (int qt = 0; qt < 2; ++qt)
          O[cd][qt] = __builtin_amdgcn_mfma_f32_16x16x32_bf16(av[cd], bp[qt], O[cd][qt], 0, 0, 0);
    }
    // xp[b][q][h*32 + d]: lane holds 4 consecutive d -> 8B packed store
#pragma unroll
    for (int qt = 0; qt < 2; ++qt) {
      int q = qbase + qt * 16 + lm;
#pragma unroll
      for (int cd = 0; cd < 2; ++cd) {
        s16x4 pk;
#pragma unroll
        for (int r = 0; r < 4; ++r) pk[r] = (short)f2bf(O[cd][qt][r]);
        *(s16x4*)(xp + ((size_t)b * 256 + q) * 128 + h * 32 + cd * 16 + lg * 4) = pk;
      }
    }
  }
}

// ---------------- output projection: x = xp @ pw^T + pb (f32 out) ----------------
__global__ __launch_bounds__(256) void kp(const unsigned short* __restrict__ xp,
    const unsigned short* __restrict__ pwb, const float* __restrict__ pb,
    float* __restrict__ xout) {
  __shared__ unsigned short xL[64][136];
  int b = blockIdx.x >> 2, r0 = (blockIdx.x & 3) << 6;
  int t = threadIdx.x;
  const unsigned short* src = xp + ((size_t)b * 256 + r0) * 128;
#pragma unroll
  for (int i = 0; i < 4; ++i) {
    int idx = t + i * 256;                   // 1024 segs: 64 rows x 16 segs of 8
    *(s16x8*)&xL[idx >> 4][(idx & 15) * 8] = *(const s16x8*)(src + idx * 8);
  }
  __syncthreads();
  int w = t >> 6, l = t & 63, lm = l & 15, lg = l >> 4;
  f32x4 acc[8];
#pragma unroll
  for (int i = 0; i < 8; ++i) acc[i] = (f32x4){0.f, 0.f, 0.f, 0.f};
#pragma unroll
  for (int kk = 0; kk < 4; ++kk) {
    s16x8 a = *(const s16x8*)&xL[w * 16 + lm][kk * 32 + lg * 8];
#pragma unroll
    for (int ct = 0; ct < 8; ++ct) {
      s16x8 bf = *(const s16x8*)(pwb + (ct * 16 + lm) * 128 + kk * 32 + lg * 8);
      acc[ct] = __builtin_amdgcn_mfma_f32_16x16x32_bf16(a, bf, acc[ct], 0, 0, 0);
    }
  }
#pragma unroll
  for (int ct = 0; ct < 8; ++ct) {
    int col = ct * 16 + lm;
    float bb = pb[col];
#pragma unroll
    for (int r = 0; r < 4; ++r) {
      int row = r0 + w * 16 + lg * 4 + r;
      xout[((size_t)b * 256 + row) * 128 + col] = acc[ct][r] + bb;
    }
  }
}

extern "C" void kernel_launch(void* const* d_in, const int* in_sizes, int n_in,
                              void* d_out, int out_size, void* d_ws, size_t ws_size,
                              hipStream_t stream) {
  const float* q    = (const float*)d_in[0];
  const float* kv   = (const float*)d_in[1];
  const float* mask = (const float*)d_in[2];
  const float* qw   = (const float*)d_in[3];
  const float* qb   = (const float*)d_in[4];
  const float* kvw  = (const float*)d_in[5];
  const float* kvb  = (const float*)d_in[6];
  const float* pw   = (const float*)d_in[7];
  const float* pb   = (const float*)d_in[8];
  const float* rpb  = (const float*)d_in[9];
  const int* relidx = (const int*)d_in[10];

  float* xout = (float*)d_out;
  float* attn = xout + (size_t)1024 * 256 * 128;   // 33,554,432

  char* ws = (char*)d_ws;
  unsigned short* qwb  = (unsigned short*)ws;                 // 32 KB
  unsigned short* kvwb = (unsigned short*)(ws + 32768);       // 64 KB
  unsigned short* pwb  = (unsigned short*)(ws + 98304);       // 32 KB
  float*          bm   = (float*)(ws + 131072);               // 32 MB
  unsigned short* qh   = (unsigned short*)(ws + 131072 + 33554432);  // 64 MB
  unsigned short* kws  = qh  + (size_t)33554432;              // 32 MB
  unsigned short* vT   = kws + (size_t)16777216;              // 32 MB
  unsigned short* xp   = vT  + (size_t)16777216;              // 64 MB

  kw_prep<<<2048, 256, 0, stream>>>(qw, kvw, pw, rpb, relidx, mask, qwb, kvwb, pwb, bm);
  kq<<<4096, 256, 0, stream>>>(q, qwb, qb, qh);
  kkv<<<2048, 256, 0, stream>>>(kv, kvwb, kvb, kws, vT);
  katt3<<<4096, 256, 0, stream>>>(qh, kws, vT, bm, attn, xp);
  kp<<<4096, 256, 0, stream>>>(xp, pwb, pb, xout);
}

// Round 5
// 426.618 us; speedup vs baseline: 2.2829x; 1.3369x over previous
//
#include <hip/hip_runtime.h>

// WindowAttention3D: B=1024, N1=256, N2=128, C=128, NH=4, hd=32, nW=64
// out = [x (1024*256*128 f32)] ++ [attn (1024*4*256*128 f32)]
// All global stores are LDS-restaged to full 128B-line granularity.

typedef __attribute__((ext_vector_type(8))) short s16x8;
typedef __attribute__((ext_vector_type(4))) short s16x4;
typedef __attribute__((ext_vector_type(4))) float f32x4;

static __device__ __forceinline__ unsigned short f2bf(float f) {
  union { float f; unsigned u; } v; v.f = f;
  unsigned r = v.u + 0x7FFFu + ((v.u >> 16) & 1u);
  return (unsigned short)(r >> 16);
}

// ---------------- prep: weights->bf16, combined bias+mask table ----------------
// bm[w][h][q][n2] = rpb[rel_index[q][n2]][h] + mask[w][q][n2]   (f32, 32 MB)
__global__ void kw_prep(const float* __restrict__ qw, const float* __restrict__ kvw,
                        const float* __restrict__ pw, const float* __restrict__ rpb,
                        const int* __restrict__ relidx, const float* __restrict__ mask,
                        unsigned short* __restrict__ qwb, unsigned short* __restrict__ kvwb,
                        unsigned short* __restrict__ pwb, float* __restrict__ bm) {
  int tid = blockIdx.x * 256 + threadIdx.x;
  int stride = gridDim.x * 256;
  for (int i = tid; i < 65536; i += stride) {
    if (i < 16384)      qwb[i] = f2bf(qw[i]);
    else if (i < 49152) kvwb[i - 16384] = f2bf(kvw[i - 16384]);
    else                pwb[i - 49152] = f2bf(pw[i - 49152]);
  }
  for (int i = tid; i < 2097152; i += stride) {
    int wdw = i >> 15, j = i & 32767;
    int rel = relidx[j];
    float4 tv = *(const float4*)(rpb + rel * 4);
    float mk = mask[i];
    float* d = bm + (size_t)(wdw * 4) * 32768 + j;
    d[0]      = tv.x + mk;
    d[32768]  = tv.y + mk;
    d[65536]  = tv.z + mk;
    d[98304]  = tv.w + mk;
  }
}

// ---------------- q projection: qh[b][h][q][32] = (q @ qw^T + qb) * scale ----------------
__global__ __launch_bounds__(256) void kq(const float* __restrict__ q,
    const unsigned short* __restrict__ qwb, const float* __restrict__ qb,
    unsigned short* __restrict__ qh) {
  __shared__ unsigned short qL[64][136];
  __shared__ unsigned short oL[64][136];
  int b = blockIdx.x >> 2, q0 = (blockIdx.x & 3) << 6;
  int t = threadIdx.x;
  const float4* src = (const float4*)(q + (b * 256 + q0) * 128);
#pragma unroll
  for (int i = 0; i < 8; ++i) {
    int idx = t + i * 256;                 // 2048 float4 = 64 rows x 128 f32
    float4 v = src[idx];
    s16x4 pk; pk[0] = (short)f2bf(v.x); pk[1] = (short)f2bf(v.y);
    pk[2] = (short)f2bf(v.z); pk[3] = (short)f2bf(v.w);
    *(s16x4*)&qL[idx >> 5][(idx & 31) * 4] = pk;
  }
  __syncthreads();
  int w = t >> 6, l = t & 63, lm = l & 15, lg = l >> 4;
  f32x4 acc[8];
#pragma unroll
  for (int i = 0; i < 8; ++i) acc[i] = (f32x4){0.f, 0.f, 0.f, 0.f};
#pragma unroll
  for (int kk = 0; kk < 4; ++kk) {
    s16x8 a = *(const s16x8*)&qL[w * 16 + lm][kk * 32 + lg * 8];
#pragma unroll
    for (int ct = 0; ct < 8; ++ct) {
      s16x8 bf = *(const s16x8*)(qwb + (ct * 16 + lm) * 128 + kk * 32 + lg * 8);
      acc[ct] = __builtin_amdgcn_mfma_f32_16x16x32_bf16(a, bf, acc[ct], 0, 0, 0);
    }
  }
  const float SC = 0.17677669529663687f;   // 32^-0.5
#pragma unroll
  for (int ct = 0; ct < 8; ++ct) {
    int col = ct * 16 + lm;
    float bb = qb[col];
#pragma unroll
    for (int r = 0; r < 4; ++r)
      oL[w * 16 + lg * 4 + r][col] = f2bf((acc[ct][r] + bb) * SC);
  }
  __syncthreads();
  // cooperative full-line store: per head, 64 rows x 64B = 4KB contiguous
  int o = t * 8, row = o >> 5, cs = o & 31;
#pragma unroll
  for (int h = 0; h < 4; ++h) {
    s16x8 v = *(const s16x8*)&oL[row][h * 32 + cs];
    *(s16x8*)(qh + ((size_t)(b * 4 + h) * 256 + q0 + row) * 32 + cs) = v;
  }
}

// ---------------- kv projection: kws[b][h][n2][32], vT[b][h][dh][n2] ----------------
__global__ __launch_bounds__(256) void kkv(const float* __restrict__ kv,
    const unsigned short* __restrict__ kvwb, const float* __restrict__ kvb,
    unsigned short* __restrict__ kws, unsigned short* __restrict__ vT) {
  __shared__ unsigned short kvL[64][136];
  __shared__ unsigned short oK[64][136];
  __shared__ unsigned short oV[128][72];
  int b = blockIdx.x >> 1, r0 = (blockIdx.x & 1) << 6;
  int t = threadIdx.x;
  const float4* src = (const float4*)(kv + (b * 128 + r0) * 128);
#pragma unroll
  for (int i = 0; i < 8; ++i) {
    int idx = t + i * 256;
    float4 v = src[idx];
    s16x4 pk; pk[0] = (short)f2bf(v.x); pk[1] = (short)f2bf(v.y);
    pk[2] = (short)f2bf(v.z); pk[3] = (short)f2bf(v.w);
    *(s16x4*)&kvL[idx >> 5][(idx & 31) * 4] = pk;
  }
  __syncthreads();
  int w = t >> 6, l = t & 63, lm = l & 15, lg = l >> 4;
  f32x4 acc[16];
#pragma unroll
  for (int i = 0; i < 16; ++i) acc[i] = (f32x4){0.f, 0.f, 0.f, 0.f};
#pragma unroll
  for (int kk = 0; kk < 4; ++kk) {
    s16x8 a = *(const s16x8*)&kvL[w * 16 + lm][kk * 32 + lg * 8];
#pragma unroll
    for (int ct = 0; ct < 16; ++ct) {
      s16x8 bf = *(const s16x8*)(kvwb + (ct * 16 + lm) * 128 + kk * 32 + lg * 8);
      acc[ct] = __builtin_amdgcn_mfma_f32_16x16x32_bf16(a, bf, acc[ct], 0, 0, 0);
    }
  }
#pragma unroll
  for (int ct = 0; ct < 16; ++ct) {
    int col = ct * 16 + lm;
    float bb = kvb[col];
    if (col < 128) {            // k part -> oK[n2_local][col]
#pragma unroll
      for (int r = 0; r < 4; ++r)
        oK[w * 16 + lg * 4 + r][col] = f2bf(acc[ct][r] + bb);
    } else {                    // v part -> oV[d][n2_local], 4 consecutive n2 per lane
      int d = col - 128;
      s16x4 pk;
#pragma unroll
      for (int r = 0; r < 4; ++r) pk[r] = (short)f2bf(acc[ct][r] + bb);
      *(s16x4*)&oV[d][w * 16 + lg * 4] = pk;
    }
  }
  __syncthreads();
  // k store: per head 64 rows x 64B = 4KB contiguous
  {
    int o = t * 8, row = o >> 5, cs = o & 31;
#pragma unroll
    for (int h = 0; h < 4; ++h) {
      s16x8 v = *(const s16x8*)&oK[row][h * 32 + cs];
      *(s16x8*)(kws + ((size_t)(b * 4 + h) * 128 + r0 + row) * 32 + cs) = v;
    }
  }
  // v store: per d-row 64 n2 x 2B = 128B aligned line
#pragma unroll
  for (int i = 0; i < 4; ++i) {
    int o = (t + i * 256) * 8;
    int d = o >> 6, ns = o & 63;
    s16x8 v = *(const s16x8*)&oV[d][ns];
    *(s16x8*)(vT + ((size_t)b * 128 + d) * 128 + r0 + ns) = v;
  }
}

// ---------------- fused attention per (b, h) ----------------
__global__ __launch_bounds__(256) void katt4(const unsigned short* __restrict__ qh,
    const unsigned short* __restrict__ kws, const unsigned short* __restrict__ vT,
    const float* __restrict__ bm, float* __restrict__ attn_out,
    unsigned short* __restrict__ xp) {
  __shared__ unsigned short kL[128][40];            // k_h [n2][dh]
  __shared__ unsigned short vTL[32][136];           // vT_h [dh][n2]
  __shared__ float scratch[4][2176] __attribute__((aligned(16))); // per-wave: aSt[16][136] f32 / xSt[32][40] bf16
  int b = blockIdx.x >> 2, h = blockIdx.x & 3;
  int t = threadIdx.x;
  const unsigned short* ksrc = kws + (size_t)(b * 4 + h) * 4096;
  const unsigned short* vsrc = vT + (size_t)(b * 4 + h) * 4096;
#pragma unroll
  for (int i = 0; i < 2; ++i) {
    int idx = t + i * 256;                   // 128 rows x 4 segs of 8
    *(s16x8*)&kL[idx >> 2][(idx & 3) * 8] = *(const s16x8*)(ksrc + idx * 8);
  }
#pragma unroll
  for (int i = 0; i < 2; ++i) {
    int idx = t + i * 256;                   // 32 rows x 16 segs of 8
    *(s16x8*)&vTL[idx >> 4][(idx & 15) * 8] = *(const s16x8*)(vsrc + idx * 8);
  }
  __syncthreads();
  int w = t >> 6, l = t & 63, lm = l & 15, lg = l >> 4;
  float* aSt = scratch[w];                         // [16][136] f32
  unsigned short* xSt = (unsigned short*)scratch[w]; // [32][40] bf16
  const unsigned short* qsrc = qh + (size_t)(b * 4 + h) * 8192;
  const float* bmh = bm + (size_t)((b & 63) * 4 + h) * 32768;
  float* attnh = attn_out + (size_t)(b * 4 + h) * 32768;
  const f32x4 zero = {0.f, 0.f, 0.f, 0.f};

  for (int p = 0; p < 2; ++p) {
    int qbase = p * 128 + w * 32;
    s16x8 pfrag[2][4];
#pragma unroll
    for (int qt = 0; qt < 2; ++qt) {
      int q = qbase + qt * 16 + lm;
      s16x8 bq = *(const s16x8*)(qsrc + q * 32 + lg * 8);
      f32x4 S[8];  // S^T: row n2 = ct*16+lg*4+r, col q = lm
#pragma unroll
      for (int ct = 0; ct < 8; ++ct) {
        s16x8 ak = *(const s16x8*)&kL[ct * 16 + lm][lg * 8];
        S[ct] = __builtin_amdgcn_mfma_f32_16x16x32_bf16(ak, bq, zero, 0, 0, 0);
      }
      float m = -1e30f;
#pragma unroll
      for (int ct = 0; ct < 8; ++ct) {
        float4 bv = *(const float4*)(bmh + q * 128 + ct * 16 + lg * 4);
        S[ct][0] += bv.x; S[ct][1] += bv.y; S[ct][2] += bv.z; S[ct][3] += bv.w;
        m = fmaxf(m, fmaxf(fmaxf(S[ct][0], S[ct][1]), fmaxf(S[ct][2], S[ct][3])));
      }
      m = fmaxf(m, __shfl_xor(m, 16));
      m = fmaxf(m, __shfl_xor(m, 32));
      float s = 0.f;
#pragma unroll
      for (int ct = 0; ct < 8; ++ct) {
#pragma unroll
        for (int r = 0; r < 4; ++r) { S[ct][r] = __expf(S[ct][r] - m); s += S[ct][r]; }
      }
      s += __shfl_xor(s, 16);
      s += __shfl_xor(s, 32);
      float inv = 1.0f / s;
      // stage P f32 into aSt: row = q local (lm), cols n2
#pragma unroll
      for (int ct = 0; ct < 8; ++ct) {
        f32x4 pv = { S[ct][0] * inv, S[ct][1] * inv, S[ct][2] * inv, S[ct][3] * inv };
        *(f32x4*)(aSt + lm * 136 + ct * 16 + lg * 4) = pv;
      }
      // coalesced NT attn store: 16 rows x 512B contiguous, 1KB/instr
      float* adst = attnh + (qbase + qt * 16) * 128;
#pragma unroll
      for (int i = 0; i < 8; ++i) {
        int o = l * 4 + i * 256;
        int row = o >> 7, colf = o & 127;
        f32x4 v = *(const f32x4*)(aSt + row * 136 + colf);
        __builtin_nontemporal_store(v, (f32x4*)(adst + o));
      }
      // P fragments for PV (read back f32, convert to bf16)
#pragma unroll
      for (int kk = 0; kk < 4; ++kk) {
        const float* pp = aSt + lm * 136 + kk * 32 + lg * 8;
        f32x4 a0 = *(const f32x4*)pp, a1 = *(const f32x4*)(pp + 4);
        s16x8 pk;
        pk[0] = (short)f2bf(a0[0]); pk[1] = (short)f2bf(a0[1]);
        pk[2] = (short)f2bf(a0[2]); pk[3] = (short)f2bf(a0[3]);
        pk[4] = (short)f2bf(a1[0]); pk[5] = (short)f2bf(a1[1]);
        pk[6] = (short)f2bf(a1[2]); pk[7] = (short)f2bf(a1[3]);
        pfrag[qt][kk] = pk;
      }
    }
    // ---- O^T = vT @ P^T ----
    f32x4 O[2][2];   // [cd][qt]
#pragma unroll
    for (int cd = 0; cd < 2; ++cd)
#pragma unroll
      for (int qt = 0; qt < 2; ++qt) O[cd][qt] = zero;
#pragma unroll
    for (int kk = 0; kk < 4; ++kk) {
      s16x8 av[2];
#pragma unroll
      for (int cd = 0; cd < 2; ++cd) av[cd] = *(const s16x8*)&vTL[cd * 16 + lm][kk * 32 + lg * 8];
#pragma unroll
      for (int cd = 0; cd < 2; ++cd)
#pragma unroll
        for (int qt = 0; qt < 2; ++qt)
          O[cd][qt] = __builtin_amdgcn_mfma_f32_16x16x32_bf16(av[cd], pfrag[qt][kk], O[cd][qt], 0, 0, 0);
    }
    // stage X tile bf16 (reuse scratch), then full-line xp store
#pragma unroll
    for (int qt = 0; qt < 2; ++qt)
#pragma unroll
      for (int cd = 0; cd < 2; ++cd) {
        s16x4 pk;
#pragma unroll
        for (int r = 0; r < 4; ++r) pk[r] = (short)f2bf(O[cd][qt][r]);
        *(s16x4*)(xSt + (qt * 16 + lm) * 40 + cd * 16 + lg * 4) = pk;
      }
    unsigned short* xdst = xp + ((size_t)(b * 4 + h) * 256 + qbase) * 32;
#pragma unroll
    for (int i = 0; i < 2; ++i) {
      int o = l * 8 + i * 512;
      int row = o >> 5, cs = o & 31;
      s16x8 v = *(const s16x8*)(xSt + row * 40 + cs);
      *(s16x8*)(xdst + o) = v;
    }
  }
}

// ---------------- output projection: x = xp @ pw^T + pb (f32 out) ----------------
__global__ __launch_bounds__(256) void kp(const unsigned short* __restrict__ xp,
    const unsigned short* __restrict__ pwb, const float* __restrict__ pb,
    float* __restrict__ xout) {
  __shared__ unsigned short xL[64][136];
  __shared__ float oX[64][132];
  int b = blockIdx.x >> 2, r0 = (blockIdx.x & 3) << 6;
  int t = threadIdx.x;
  {
    int o = t * 8, row = o >> 5, cs = o & 31;
#pragma unroll
    for (int h = 0; h < 4; ++h) {
      s16x8 v = *(const s16x8*)(xp + ((size_t)(b * 4 + h) * 256 + r0 + row) * 32 + cs);
      *(s16x8*)&xL[row][h * 32 + cs] = v;
    }
  }
  __syncthreads();
  int w = t >> 6, l = t & 63, lm = l & 15, lg = l >> 4;
  f32x4 acc[8];
#pragma unroll
  for (int i = 0; i < 8; ++i) acc[i] = (f32x4){0.f, 0.f, 0.f, 0.f};
#pragma unroll
  for (int kk = 0; kk < 4; ++kk) {
    s16x8 a = *(const s16x8*)&xL[w * 16 + lm][kk * 32 + lg * 8];
#pragma unroll
    for (int ct = 0; ct < 8; ++ct) {
      s16x8 bf = *(const s16x8*)(pwb + (ct * 16 + lm) * 128 + kk * 32 + lg * 8);
      acc[ct] = __builtin_amdgcn_mfma_f32_16x16x32_bf16(a, bf, acc[ct], 0, 0, 0);
    }
  }
#pragma unroll
  for (int ct = 0; ct < 8; ++ct) {
    int col = ct * 16 + lm;
    float bb = pb[col];
#pragma unroll
    for (int r = 0; r < 4; ++r)
      oX[w * 16 + lg * 4 + r][col] = acc[ct][r] + bb;
  }
  __syncthreads();
  float* xdst = xout + ((size_t)b * 256 + r0) * 128;
#pragma unroll
  for (int i = 0; i < 8; ++i) {
    int o = (t + i * 256) * 4;
    int row = o >> 7, colf = o & 127;
    f32x4 v = *(const f32x4*)&oX[row][colf];
    __builtin_nontemporal_store(v, (f32x4*)(xdst + o));
  }
}

extern "C" void kernel_launch(void* const* d_in, const int* in_sizes, int n_in,
                              void* d_out, int out_size, void* d_ws, size_t ws_size,
                              hipStream_t stream) {
  const float* q    = (const float*)d_in[0];
  const float* kv   = (const float*)d_in[1];
  const float* mask = (const float*)d_in[2];
  const float* qw   = (const float*)d_in[3];
  const float* qb   = (const float*)d_in[4];
  const float* kvw  = (const float*)d_in[5];
  const float* kvb  = (const float*)d_in[6];
  const float* pw   = (const float*)d_in[7];
  const float* pb   = (const float*)d_in[8];
  const float* rpb  = (const float*)d_in[9];
  const int* relidx = (const int*)d_in[10];

  float* xout = (float*)d_out;
  float* attn = xout + (size_t)1024 * 256 * 128;   // 33,554,432

  char* ws = (char*)d_ws;
  unsigned short* qwb  = (unsigned short*)ws;                 // 32 KB
  unsigned short* kvwb = (unsigned short*)(ws + 32768);       // 64 KB
  unsigned short* pwb  = (unsigned short*)(ws + 98304);       // 32 KB
  float*          bm   = (float*)(ws + 131072);               // 32 MB
  unsigned short* qh   = (unsigned short*)(ws + 131072 + 33554432);  // 64 MB
  unsigned short* kws  = qh  + (size_t)33554432;              // 32 MB
  unsigned short* vT   = kws + (size_t)16777216;              // 32 MB
  unsigned short* xp   = vT  + (size_t)16777216;              // 64 MB

  kw_prep<<<2048, 256, 0, stream>>>(qw, kvw, pw, rpb, relidx, mask, qwb, kvwb, pwb, bm);
  kq<<<4096, 256, 0, stream>>>(q, qwb, qb, qh);
  kkv<<<2048, 256, 0, stream>>>(kv, kvwb, kvb, kws, vT);
  katt4<<<4096, 256, 0, stream>>>(qh, kws, vT, bm, attn, xp);
  kp<<<4096, 256, 0, stream>>>(xp, pwb, pb, xout);
}